// Round 5
// baseline (79.763 us; speedup 1.0000x reference)
//
#include <hip/hip_runtime.h>
#include <hip/hip_bf16.h>
#include <hip/hip_cooperative_groups.h>

namespace cg = cooperative_groups;

#define B_ 8
#define G_ 1024
#define HD_ 1024
#define EPS_ 1e-5f

// NOTE: The reference's BatchNorm over the G axis (training mode, batch stats)
// makes the output invariant to any per-(b,j) constant added to H @ fc_w.T.
// The broadcast-qemb half of H and fc_b are such constants -> the whole GIN
// pipeline (fc_init, graph agg, bn1/bn2, mean-pool, r0) cannot affect d_out.
// Only gPos, allDBGEmb, fc_w[:,1024:], bn3, fc2 matter.  (Verified: R3 full
// pipeline and R4 reduced pipeline give identical absmax.)

typedef __attribute__((ext_vector_type(8))) short bf16x8;
typedef __attribute__((ext_vector_type(16))) float f32x16;

__device__ inline short bf1(float x) {
    return (short)__builtin_bit_cast(unsigned short, __float2bfloat16(x));
}
__device__ inline bf16x8 cvt8(float4 a, float4 b) {
    bf16x8 o;
    o[0] = bf1(a.x); o[1] = bf1(a.y); o[2] = bf1(a.z); o[3] = bf1(a.w);
    o[4] = bf1(b.x); o[5] = bf1(b.y); o[6] = bf1(b.z); o[7] = bf1(b.w);
    return o;
}

// LDS slab layouts: slab = 8-element k-chunk; slab stride rows*8+2 shorts so
// consecutive slabs shift by one dword bank -> ~2-way conflicts max.
#define ASLAB 258   // 32 rows * 8 + 2
#define BSLAB 1026  // 128 rows * 8 + 2

// One cooperative kernel: GEMM (acc in regs) -> partial BN sums -> grid.sync
// -> stats -> BN+relu+fc2+sigmoid straight from the accumulator.
// grid (32, 8) = 256 blocks (1/CU), 256 thr, ~84 KB LDS.
__global__ __launch_bounds__(256) void k_fused(const int* __restrict__ gPos,
                                               const float* __restrict__ emb,
                                               const float* __restrict__ fc_w,
                                               const float* __restrict__ g3,
                                               const float* __restrict__ b3,
                                               const float* __restrict__ fc2w,
                                               const float* __restrict__ fc2b,
                                               float* __restrict__ ps,
                                               float* __restrict__ pq,
                                               float* __restrict__ out) {
    int b = blockIdx.y, gblk = blockIdx.x;
    int gbase = gblk * 32;
    int tid = threadIdx.x;
    int jq = tid >> 6, lane = tid & 63;
    int l31 = lane & 31, kh = lane >> 5;

    __shared__ int gidx[32];
    __shared__ short As[2][16 * ASLAB];
    __shared__ short Bs[2][16 * BSLAB];
    __shared__ float scL[128], shL[128];
    __shared__ float wred[4][32];

    if (tid < 32) gidx[tid] = gPos[b * G_ + gbase + tid];
    __syncthreads();

    int arow = tid >> 3, acp = tid & 7;   // A staging: 8 threads per emb row
    int brow = tid >> 1, bpar = tid & 1;  // B staging: 2 threads per fc_w row
    const float* abase = emb + (size_t)gidx[arow] * HD_;
    const float* bbase = fc_w + (size_t)brow * (2 * HD_) + HD_;

    f32x16 acc;
#pragma unroll
    for (int i = 0; i < 16; ++i) acc[i] = 0.f;

    // prologue: stage phase 0 into buffer 0
    {
        const float4* ap = (const float4*)(abase + acp * 8);
#pragma unroll
        for (int i = 0; i < 2; ++i)
            *(bf16x8*)&As[0][(acp + 8 * i) * ASLAB + arow * 8] =
                cvt8(ap[i * 16], ap[i * 16 + 1]);
        const float4* bp = (const float4*)(bbase + bpar * 8);
#pragma unroll
        for (int i = 0; i < 8; ++i)
            *(bf16x8*)&Bs[0][(bpar + 2 * i) * BSLAB + brow * 8] =
                cvt8(bp[i * 4], bp[i * 4 + 1]);
    }
    __syncthreads();

    for (int p = 0; p < 8; ++p) {
        int cur = p & 1;
        if (p < 7) {
            int nxt = cur ^ 1;
            const float4* ap = (const float4*)(abase + (p + 1) * 128 + acp * 8);
#pragma unroll
            for (int i = 0; i < 2; ++i)
                *(bf16x8*)&As[nxt][(acp + 8 * i) * ASLAB + arow * 8] =
                    cvt8(ap[i * 16], ap[i * 16 + 1]);
            const float4* bp = (const float4*)(bbase + (p + 1) * 128 + bpar * 8);
#pragma unroll
            for (int i = 0; i < 8; ++i)
                *(bf16x8*)&Bs[nxt][(bpar + 2 * i) * BSLAB + brow * 8] =
                    cvt8(bp[i * 4], bp[i * 4 + 1]);
        }
#pragma unroll
        for (int kt = 0; kt < 8; ++kt) {
            int c = kt * 2 + kh;
            bf16x8 a = *(const bf16x8*)&As[cur][c * ASLAB + l31 * 8];
            bf16x8 bv = *(const bf16x8*)&Bs[cur][c * BSLAB + (jq * 32 + l31) * 8];
            acc = __builtin_amdgcn_mfma_f32_32x32x16_bf16(a, bv, acc, 0, 0, 0);
        }
        __syncthreads();
    }

    // per-block BN partial sums (no atomics)
    int jcol = jq * 32 + l31;
    {
        float s = 0.f, q = 0.f;
#pragma unroll
        for (int r = 0; r < 16; ++r) {
            float v = acc[r];
            s += v;
            q += v * v;
        }
        s += __shfl_xor(s, 32, 64);
        q += __shfl_xor(q, 32, 64);
        if (lane < 32) {
            ps[(b * 32 + gblk) * 128 + jcol] = s;
            pq[(b * 32 + gblk) * 128 + jcol] = q;
        }
    }

    __threadfence();
    cg::this_grid().sync();

    // stats: every block (redundantly per b) reduces 32 partials -> scale/shift
    if (tid < 128) {
        int j = tid;
        float ss = 0.f, qq = 0.f;
#pragma unroll 8
        for (int t = 0; t < 32; ++t) {
            ss += ps[(b * 32 + t) * 128 + j];
            qq += pq[(b * 32 + t) * 128 + j];
        }
        float mu = ss * (1.f / G_);
        float var = qq * (1.f / G_) - mu * mu;
        float sc = g3[j] * rsqrtf(var + EPS_);
        scL[j] = sc;
        shL[j] = b3[j] - mu * sc;
    }
    __syncthreads();

    // epilogue: BN + relu + fc2 dot over j, straight from regs
    float sc = scL[jcol], sh = shL[jcol], wv = fc2w[jcol];
    float rsum[16];
#pragma unroll
    for (int r = 0; r < 16; ++r) {
        float v = fmaxf(fmaf(acc[r], sc, sh), 0.f) * wv;
        v += __shfl_xor(v, 1, 64);
        v += __shfl_xor(v, 2, 64);
        v += __shfl_xor(v, 4, 64);
        v += __shfl_xor(v, 8, 64);
        v += __shfl_xor(v, 16, 64);  // sum over the 32-lane j-group
        rsum[r] = v;
    }
    if (l31 == 0) {
#pragma unroll
        for (int r = 0; r < 16; ++r)
            wred[jq][(r & 3) + 8 * (r >> 2) + 4 * kh] = rsum[r];
    }
    __syncthreads();
    if (tid < 32) {
        float tot = wred[0][tid] + wred[1][tid] + wred[2][tid] + wred[3][tid] + fc2b[0];
        out[b * G_ + gbase + tid] = 1.f / (1.f + expf(-tot));
    }
}

extern "C" void kernel_launch(void* const* d_in, const int* in_sizes, int n_in,
                              void* d_out, int out_size, void* d_ws, size_t ws_size,
                              hipStream_t stream) {
    const int*   gPos = (const int*)d_in[3];
    const float* emb  = (const float*)d_in[4];
    const float* fc_w = (const float*)d_in[11];
    const float* bn3g = (const float*)d_in[13];
    const float* bn3b = (const float*)d_in[14];
    const float* fc2w = (const float*)d_in[15];
    const float* fc2b = (const float*)d_in[16];
    float* out = (float*)d_out;

    char* w = (char*)d_ws;
    float* ps = (float*)w; w += (size_t)B_ * 32 * 128 * 4;
    float* pq = (float*)w; w += (size_t)B_ * 32 * 128 * 4;

    void* args[] = {(void*)&gPos, (void*)&emb, (void*)&fc_w, (void*)&bn3g, (void*)&bn3b,
                    (void*)&fc2w, (void*)&fc2b, (void*)&ps, (void*)&pq, (void*)&out};
    hipLaunchCooperativeKernel((const void*)k_fused, dim3(32, B_), dim3(256, 1, 1),
                               args, 0, stream);
}

// Round 6
// 28.970 us; speedup vs baseline: 2.7533x; 2.7533x over previous
//
#include <hip/hip_runtime.h>
#include <hip/hip_bf16.h>

#define B_ 8
#define G_ 1024
#define HD_ 1024
#define EPS_ 1e-5f

// NOTE: The reference's BatchNorm over the G axis (training mode, batch stats)
// makes the output invariant to any per-(b,j) constant added to H @ fc_w.T.
// The broadcast-qemb half of H and fc_b are such constants -> the whole GIN
// pipeline cannot affect d_out. Only gPos, allDBGEmb, fc_w[:,1024:], bn3, fc2
// matter. (Verified R3 vs R4: identical absmax.)
// R5 lesson: cooperative launch + grid.sync costs ~45 us here -> stay multi-kernel.

typedef __attribute__((ext_vector_type(8))) short bf16x8;
typedef __attribute__((ext_vector_type(4))) float f32x4;

__device__ inline short bf1(float x) {
    return (short)__builtin_bit_cast(unsigned short, __float2bfloat16(x));
}
__device__ inline bf16x8 cvt8(float4 a, float4 b) {
    bf16x8 o;
    o[0] = bf1(a.x); o[1] = bf1(a.y); o[2] = bf1(a.z); o[3] = bf1(a.w);
    o[4] = bf1(b.x); o[5] = bf1(b.y); o[6] = bf1(b.z); o[7] = bf1(b.w);
    return o;
}

// ---------- fc_w[:,1024:2048] -> bf16 in MFMA B-fragment order ----------
// frag index f = kt*8 + jblk (kt = k/32, jblk = j/16); within frag, lane l
// holds B[k = kt*32 + (l>>4)*8 + i][j = jblk*16 + (l&15)], i = 0..7.
__global__ __launch_bounds__(256) void k_w2cvt(const float* __restrict__ fc_w,
                                               short* __restrict__ w2arr) {
    int gid = blockIdx.x * 256 + threadIdx.x;  // 0 .. 32*8*64-1
    int kt = gid >> 9;
    int jblk = (gid >> 6) & 7;
    int lane = gid & 63;
    int j = jblk * 16 + (lane & 15);
    int k = kt * 32 + (lane >> 4) * 8;
    const float4* sp = (const float4*)&fc_w[(size_t)j * (2 * HD_) + HD_ + k];
    *(bf16x8*)&w2arr[(size_t)gid * 8] = cvt8(sp[0], sp[1]);
}

#define ASLAB 258  // 32 rows * 8 shorts + 2 pad per 8-k slab

// ---------- z[b][g][j] = emb[gPos[b][g]] . fc_w[j][1024:2048] ----------
// grid (32, 8), 512 thr = 8 waves; wave (gq,jq) does 16g x 32j via 16x16x32.
// A: LDS double-buffered (gathered emb rows, f32->bf16). B: direct from w2arr
// (register fragments, L2-resident, no LDS).
__global__ __launch_bounds__(512) void k_gemm(const int* __restrict__ gPos,
                                              const float* __restrict__ emb,
                                              const short* __restrict__ w2arr,
                                              float* __restrict__ z,
                                              float* __restrict__ ps,
                                              float* __restrict__ pq) {
    int b = blockIdx.y, gblk = blockIdx.x;
    int gbase = gblk * 32;
    int tid = threadIdx.x;
    int wave = tid >> 6, lane = tid & 63;
    int gq = wave >> 2, jq = wave & 3;
    int l15 = lane & 15, kb = lane >> 4;  // kb = 0..3

    __shared__ int gidx[32];
    __shared__ short As[2][16 * ASLAB];

    if (tid < 32) gidx[tid] = gPos[b * G_ + gbase + tid];
    __syncthreads();

    int arow = tid >> 4, acp = tid & 15;  // 512 thr: one bf16x8 slab piece each
    const float* abase = emb + (size_t)gidx[arow] * HD_;

    f32x4 acc0 = {0.f, 0.f, 0.f, 0.f}, acc1 = {0.f, 0.f, 0.f, 0.f};

    {   // prologue: stage phase 0
        const float4* ap = (const float4*)(abase + acp * 8);
        *(bf16x8*)&As[0][acp * ASLAB + arow * 8] = cvt8(ap[0], ap[1]);
    }
    __syncthreads();

    for (int p = 0; p < 8; ++p) {
        int cur = p & 1;
        if (p < 7) {
            const float4* ap = (const float4*)(abase + (p + 1) * 128 + acp * 8);
            *(bf16x8*)&As[cur ^ 1][acp * ASLAB + arow * 8] = cvt8(ap[0], ap[1]);
        }
#pragma unroll
        for (int kt = 0; kt < 4; ++kt) {
            bf16x8 a = *(const bf16x8*)&As[cur][(kt * 4 + kb) * ASLAB + (gq * 16 + l15) * 8];
            int f = (p * 4 + kt) * 8 + jq * 2;
            bf16x8 b0 = *(const bf16x8*)&w2arr[((size_t)f * 64 + lane) * 8];
            bf16x8 b1 = *(const bf16x8*)&w2arr[((size_t)(f + 1) * 64 + lane) * 8];
            acc0 = __builtin_amdgcn_mfma_f32_16x16x32_bf16(a, b0, acc0, 0, 0, 0);
            acc1 = __builtin_amdgcn_mfma_f32_16x16x32_bf16(a, b1, acc1, 0, 0, 0);
        }
        __syncthreads();
    }

    // epilogue: z write + per-(gblk,gq) BN partials (no atomics)
    int col0 = jq * 32 + l15, col1 = col0 + 16;
    float s0 = 0.f, q0 = 0.f, s1 = 0.f, q1 = 0.f;
#pragma unroll
    for (int r = 0; r < 4; ++r) {
        int g = gbase + gq * 16 + kb * 4 + r;  // C/D: col=lane&15, row=(lane>>4)*4+reg
        float z0 = acc0[r], z1 = acc1[r];
        z[(size_t)(b * G_ + g) * 128 + col0] = z0;
        z[(size_t)(b * G_ + g) * 128 + col1] = z1;
        s0 += z0; q0 += z0 * z0;
        s1 += z1; q1 += z1 * z1;
    }
    s0 += __shfl_xor(s0, 16, 64); s0 += __shfl_xor(s0, 32, 64);
    q0 += __shfl_xor(q0, 16, 64); q0 += __shfl_xor(q0, 32, 64);
    s1 += __shfl_xor(s1, 16, 64); s1 += __shfl_xor(s1, 32, 64);
    q1 += __shfl_xor(q1, 16, 64); q1 += __shfl_xor(q1, 32, 64);
    if (lane < 16) {
        int slot = (b * 64 + gblk * 2 + gq) * 128;
        ps[slot + col0] = s0; pq[slot + col0] = q0;
        ps[slot + col1] = s1; pq[slot + col1] = q1;
    }
}

// ---------- BN3 stats: reduce 64 block-partials -> scale/shift per (b,j) ----------
__global__ void k_stats(const float* __restrict__ ps, const float* __restrict__ pq,
                        const float* __restrict__ g3, const float* __restrict__ b3,
                        float* __restrict__ scv, float* __restrict__ shv) {
    int b = blockIdx.x, j = threadIdx.x;
    float s = 0.f, q = 0.f;
#pragma unroll 8
    for (int t = 0; t < 64; ++t) {
        s += ps[(b * 64 + t) * 128 + j];
        q += pq[(b * 64 + t) * 128 + j];
    }
    float mu = s * (1.f / G_);
    float var = q * (1.f / G_) - mu * mu;
    float sc = g3[j] * rsqrtf(var + EPS_);
    scv[b * 128 + j] = sc;
    shv[b * 128 + j] = b3[j] - mu * sc;
}

// ---------- BN3 apply + relu + fc2 dot + sigmoid; one wave per (b,g) ----------
__global__ __launch_bounds__(256) void k_final(const float* __restrict__ z,
                                               const float* __restrict__ scv,
                                               const float* __restrict__ shv,
                                               const float* __restrict__ fc2w,
                                               const float* __restrict__ fc2b,
                                               float* __restrict__ out) {
    int wid = (blockIdx.x * blockDim.x + threadIdx.x) >> 6;
    int lane = threadIdx.x & 63;
    int b = wid >> 10;
    const float* zr = z + (size_t)wid * 128;
    float acc = 0.f;
#pragma unroll
    for (int t = 0; t < 2; ++t) {
        int j = lane + t * 64;
        float v = fmaf(zr[j], scv[b * 128 + j], shv[b * 128 + j]);
        v = fmaxf(v, 0.f);
        acc += v * fc2w[j];
    }
    for (int off = 32; off; off >>= 1) acc += __shfl_down(acc, off, 64);
    if (lane == 0) out[wid] = 1.f / (1.f + expf(-(acc + fc2b[0])));
}

extern "C" void kernel_launch(void* const* d_in, const int* in_sizes, int n_in,
                              void* d_out, int out_size, void* d_ws, size_t ws_size,
                              hipStream_t stream) {
    const int*   gPos = (const int*)d_in[3];
    const float* emb  = (const float*)d_in[4];
    const float* fc_w = (const float*)d_in[11];
    const float* bn3g = (const float*)d_in[13];
    const float* bn3b = (const float*)d_in[14];
    const float* fc2w = (const float*)d_in[15];
    const float* fc2b = (const float*)d_in[16];
    float* out = (float*)d_out;

    char* w = (char*)d_ws;
    float* z     = (float*)w; w += (size_t)B_ * G_ * 128 * 4;   // 4 MB
    short* w2arr = (short*)w; w += (size_t)128 * HD_ * 2;       // 256 KB
    float* ps    = (float*)w; w += (size_t)B_ * 64 * 128 * 4;   // 256 KB
    float* pq    = (float*)w; w += (size_t)B_ * 64 * 128 * 4;   // 256 KB
    float* scv   = (float*)w; w += (size_t)B_ * 128 * 4;
    float* shv   = (float*)w; w += (size_t)B_ * 128 * 4;

    k_w2cvt<<<64, 256, 0, stream>>>(fc_w, w2arr);
    k_gemm<<<dim3(32, B_), 512, 0, stream>>>(gPos, emb, w2arr, z, ps, pq);
    k_stats<<<B_, 128, 0, stream>>>(ps, pq, bn3g, bn3b, scv, shv);
    k_final<<<(B_ * G_) / 4, 256, 0, stream>>>(z, scv, shv, fc2w, fc2b, out);
}